// Round 1
// 1444.610 us; speedup vs baseline: 1.3370x; 1.3370x over previous
//
#include <hip/hip_runtime.h>
#include <cstdint>
#include <cstddef>

#define B_  64
#define S_  80
#define H_  512
#define E_  512
#define T_  30
#define V_  32000
#define TD  (T_ - 1)        // 29 decode steps
#define M_  (TD * B_)       // 1856 rows in the batched GEMMs

typedef __attribute__((ext_vector_type(8))) short s16x8;
typedef __attribute__((ext_vector_type(4))) float f32x4;
typedef __attribute__((ext_vector_type(4))) unsigned short us16x4;

// ---------------------------------------------------------------------------
// bf16 split helpers (round-to-nearest-even hi; exact residual -> lo)
// ---------------------------------------------------------------------------
__device__ __forceinline__ unsigned short f2bf(float x) {
  unsigned u = __float_as_uint(x);
  return (unsigned short)((u + 0x7FFFu + ((u >> 16) & 1u)) >> 16);
}
__device__ __forceinline__ float bf2f(unsigned short h) {
  return __uint_as_float((unsigned)h << 16);
}

// async global->LDS, 16B per lane; LDS dest is wave-uniform base + lane*16
__device__ __forceinline__ void gld16(void* lds, const void* g) {
  __builtin_amdgcn_global_load_lds(
      (const __attribute__((address_space(1))) void*)g,
      (__attribute__((address_space(3))) void*)lds, 16, 0, 0);
}

// ---------------------------------------------------------------------------
// K0: split fp32 array into bf16 hi/lo pair. n4 = count/4.
// ---------------------------------------------------------------------------
__global__ __launch_bounds__(256) void k_split(
    const float* __restrict__ src, unsigned short* __restrict__ hi,
    unsigned short* __restrict__ lo, int n4) {
  int stride = gridDim.x * 256;
  for (int i = blockIdx.x * 256 + threadIdx.x; i < n4; i += stride) {
    float4 v = ((const float4*)src)[i];
    float x[4] = {v.x, v.y, v.z, v.w};
    us16x4 h, l;
#pragma unroll
    for (int q = 0; q < 4; ++q) {
      unsigned short hb = f2bf(x[q]);
      h[q] = hb;
      l[q] = f2bf(x[q] - bf2f(hb));
    }
    ((us16x4*)hi)[i] = h;
    ((us16x4*)lo)[i] = l;
  }
}

// ---------------------------------------------------------------------------
// K1: w_enc = W1_enc^T * (W2^T * (W3^T * v_att)).  One block, 512 threads.
// All biases provably cancel in the softmax (shift-invariance).
// ---------------------------------------------------------------------------
__global__ __launch_bounds__(512) void k_attn_vec(
    const float* __restrict__ W1, const float* __restrict__ W2,
    const float* __restrict__ W3, const float* __restrict__ v_att,
    float* __restrict__ wenc) {
  __shared__ float s_a[512];
  __shared__ float s_b[512];
  int t = threadIdx.x;
  s_a[t] = v_att[t];
  __syncthreads();
  float acc = 0.f;                        // w3v[t] = sum_g W3[g,t] * v[g]
  for (int g = 0; g < 512; ++g) acc += W3[g * 512 + t] * s_a[g];
  s_b[t] = acc;
  __syncthreads();
  acc = 0.f;                              // w2v[t] = sum_g W2[g,t] * w3v[g]
  for (int g = 0; g < 512; ++g) acc += W2[g * 512 + t] * s_b[g];
  s_a[t] = acc;
  __syncthreads();
  acc = 0.f;                              // wenc[t] = sum_h W1[h, t] * w2v[h]  (t < 512)
  for (int h = 0; h < 512; ++h) acc += W1[h * 1024 + t] * s_a[h];
  wenc[t] = acc;
}

// ---------------------------------------------------------------------------
// K2: scores[b,s] = enc[b,s,:]·wenc ; softmax over s ; context[b,:] = attn·enc
// ---------------------------------------------------------------------------
__global__ __launch_bounds__(512) void k_score_ctx(
    const float* __restrict__ enc, const float* __restrict__ wenc,
    float* __restrict__ context) {
  int b = blockIdx.x;
  int t = threadIdx.x;
  __shared__ float s_w[512];
  __shared__ float s_sc[80];
  __shared__ float s_at[80];
  __shared__ float s_mx, s_inv;
  s_w[t] = wenc[t];
  __syncthreads();
  int wave = t >> 6, lane = t & 63;
  for (int s = wave; s < S_; s += 8) {
    const float* row = enc + ((size_t)b * S_ + s) * 512;
    float acc = 0.f;
    for (int c = 0; c < 8; ++c) acc += row[lane + 64 * c] * s_w[lane + 64 * c];
    for (int off = 32; off; off >>= 1) acc += __shfl_down(acc, off);
    if (lane == 0) s_sc[s] = acc;
  }
  __syncthreads();
  if (t == 0) {
    float mx = -INFINITY;
    for (int s = 0; s < S_; ++s) mx = fmaxf(mx, s_sc[s]);
    s_mx = mx;
  }
  __syncthreads();
  if (t < S_) s_at[t] = expf(s_sc[t] - s_mx);
  __syncthreads();
  if (t == 0) {
    float sm = 0.f;
    for (int s = 0; s < S_; ++s) sm += s_at[s];
    s_inv = 1.f / sm;
  }
  __syncthreads();
  float inv = s_inv;
  float acc = 0.f;                        // t indexes feature f
  for (int s = 0; s < S_; ++s) acc += s_at[s] * enc[((size_t)b * S_ + s) * 512 + t];
  context[b * 512 + t] = acc * inv;
}

// ---------------------------------------------------------------------------
// K3: gctx[b,j] = context[b,:]·W_ih[j, 512:1024] + b_ih[j]
// ---------------------------------------------------------------------------
__global__ __launch_bounds__(256) void k_gctx(
    const float* __restrict__ context, const float* __restrict__ W_ih,
    const float* __restrict__ b_ih, float* __restrict__ gctx) {
  int b = blockIdx.x;
  int t = threadIdx.x;
  __shared__ float s_c[512];
  s_c[t] = context[b * 512 + t];
  s_c[t + 256] = context[b * 512 + 256 + t];
  __syncthreads();
  int wave = t >> 6, lane = t & 63;
  for (int i = 0; i < 16; ++i) {
    int j = blockIdx.y * 64 + wave * 16 + i;
    const float* row = W_ih + (size_t)j * 1024 + 512;
    float acc = 0.f;
    for (int c = 0; c < 8; ++c) acc += row[lane + 64 * c] * s_c[lane + 64 * c];
    for (int off = 32; off; off >>= 1) acc += __shfl_down(acc, off);
    if (lane == 0) gctx[b * 1536 + j] = acc + b_ih[j];
  }
}

// ---------------------------------------------------------------------------
// K4: GIC[m,j] = emb[targets[b,t],:]·W_ih[j,0:512] + gctx[b,j],  m = t*64+b
// ---------------------------------------------------------------------------
__global__ __launch_bounds__(256) void k_giemb(
    const float* __restrict__ emb, const int* __restrict__ targets,
    const float* __restrict__ W_ih, const float* __restrict__ gctx,
    float* __restrict__ gic) {
  __shared__ float As[16][68];
  __shared__ float Bs[16][68];
  int m0 = blockIdx.x * 64;
  int j0 = blockIdx.y * 64;
  int t = threadIdx.x;
  int lr = t >> 2;              // 0..63: row within tile
  int lk = (t & 3) * 4;         // k-quad
  int m = m0 + lr;
  int tt = m >> 6, bb = m & 63;
  const float* arow = emb + (size_t)targets[bb * T_ + tt] * 512;
  const float* brow = W_ih + (size_t)(j0 + lr) * 1024;
  int tx = t & 15, ty = t >> 4;
  float acc[4][4] = {};
  for (int k0 = 0; k0 < 512; k0 += 16) {
    float4 av = *(const float4*)(arow + k0 + lk);
    float4 bv = *(const float4*)(brow + k0 + lk);
    __syncthreads();
    As[lk + 0][lr] = av.x; As[lk + 1][lr] = av.y; As[lk + 2][lr] = av.z; As[lk + 3][lr] = av.w;
    Bs[lk + 0][lr] = bv.x; Bs[lk + 1][lr] = bv.y; Bs[lk + 2][lr] = bv.z; Bs[lk + 3][lr] = bv.w;
    __syncthreads();
    for (int kk = 0; kk < 16; ++kk) {
      float4 a4 = *(const float4*)&As[kk][ty * 4];
      float4 b4 = *(const float4*)&Bs[kk][tx * 4];
      float a[4] = {a4.x, a4.y, a4.z, a4.w};
      float bb4[4] = {b4.x, b4.y, b4.z, b4.w};
      for (int i = 0; i < 4; ++i)
        for (int j = 0; j < 4; ++j) acc[i][j] += a[i] * bb4[j];
    }
  }
  for (int i = 0; i < 4; ++i) {
    int mm = m0 + ty * 4 + i;
    int bb2 = mm & 63;
    float4 v;
    int jj = j0 + tx * 4;
    v.x = acc[i][0] + gctx[bb2 * 1536 + jj + 0];
    v.y = acc[i][1] + gctx[bb2 * 1536 + jj + 1];
    v.z = acc[i][2] + gctx[bb2 * 1536 + jj + 2];
    v.w = acc[i][3] + gctx[bb2 * 1536 + jj + 3];
    *(float4*)(gic + (size_t)mm * 1536 + jj) = v;
  }
}

// ---------------------------------------------------------------------------
// K5: one GRU step. gh = h_prev@W_hh^T + b_hh ; gates ; h_out.
// ---------------------------------------------------------------------------
__global__ __launch_bounds__(256) void k_step(
    const float* __restrict__ h_prev, const float* __restrict__ W_hh,
    const float* __restrict__ b_hh, const float* __restrict__ gic_t,
    float* __restrict__ h_out) {
  int b = blockIdx.x;
  int i0 = blockIdx.y * 64;
  int t = threadIdx.x;
  __shared__ float s_h[512];
  __shared__ float s_g[3][64];
  s_h[t] = h_prev[b * 512 + t];
  s_h[256 + t] = h_prev[b * 512 + 256 + t];
  __syncthreads();
  int wave = t >> 6, lane = t & 63;
  for (int d = wave; d < 192; d += 4) {
    int part = d >> 6;          // 0=r, 1=z, 2=n
    int ii = d & 63;
    int j = part * 512 + i0 + ii;
    const float* row = W_hh + (size_t)j * 512;
    float acc = 0.f;
    for (int c = 0; c < 8; ++c) acc += row[lane + 64 * c] * s_h[lane + 64 * c];
    for (int off = 32; off; off >>= 1) acc += __shfl_down(acc, off);
    if (lane == 0) s_g[part][ii] = acc + b_hh[j];
  }
  __syncthreads();
  if (t < 64) {
    int i = i0 + t;
    float gi_r = gic_t[b * 1536 + i];
    float gi_z = gic_t[b * 1536 + 512 + i];
    float gi_n = gic_t[b * 1536 + 1024 + i];
    float r = 1.f / (1.f + expf(-(gi_r + s_g[0][t])));
    float z = 1.f / (1.f + expf(-(gi_z + s_g[1][t])));
    float n = tanhf(gi_n + r * s_g[2][t]);
    h_out[b * 512 + i] = (1.f - z) * n + z * s_h[i];
  }
}

// ---------------------------------------------------------------------------
// K6 (new): logits = Hall @ W_out^T + b_out via split-bf16 MFMA.
// A = Hall (M=1856 pad->1920), B = W_out (32000x512), K=512.
// 128x128 tile, BK=32, 256 threads = 4 waves, each wave 64x64 (4x4 frags of
// 16x16x32). 3 MFMA products per frag: hi*hi + hi*lo + lo*hi (fp32 acc).
// m97-style: global_load_lds(16B) staging, 2 barriers per K-step, linear
// [row][32] bf16 LDS (64B row stride = ds_read_b128 bank-floor, no swizzle).
// ---------------------------------------------------------------------------
__global__ __launch_bounds__(256) void k_logits_mfma(
    const unsigned short* __restrict__ Ah, const unsigned short* __restrict__ Al,
    const unsigned short* __restrict__ Bh, const unsigned short* __restrict__ Bl,
    const float* __restrict__ b_out, float* __restrict__ out) {
  __shared__ unsigned short As_h[128 * 32], As_l[128 * 32];
  __shared__ unsigned short Bs_h[128 * 32], Bs_l[128 * 32];
  int t = threadIdx.x;
  int w = t >> 6, l = t & 63;
  int m0 = blockIdx.x * 128, n0 = blockIdx.y * 128;

  // staging map: pass p: idx = p*256 + w*64 + l -> row r = idx>>2, 16B chunk c = idx&3
  int c8 = (l & 3) * 8;              // k-offset (elements) of this lane's chunk
  int rr = (w << 4) + (l >> 2);      // tile row for pass 0
  int aoff[2], boff[2];              // element offsets into A / B arrays
#pragma unroll
  for (int p = 0; p < 2; ++p) {
    int r = rr + (p << 6);
    int am = m0 + r; if (am >= M_) am = M_ - 1;   // clamp pad rows (stores guarded)
    aoff[p] = am * 512 + c8;
    boff[p] = (n0 + r) * 512 + c8;
  }

  int wr = (w >> 1) << 6;            // wave row offset: 0 / 64
  int wc = (w & 1) << 6;             // wave col offset: 0 / 64
  int lm = l & 15;
  int k8 = (l >> 4) << 3;            // k-group * 8 within BK=32
  f32x4 acc[4][4] = {};

  for (int k0 = 0; k0 < 512; k0 += 32) {
#pragma unroll
    for (int p = 0; p < 2; ++p) {
      int d = (p << 11) + (w << 9);  // LDS dest (shorts): wave-uniform
      gld16(&As_h[d], Ah + aoff[p] + k0);
      gld16(&As_l[d], Al + aoff[p] + k0);
      gld16(&Bs_h[d], Bh + boff[p] + k0);
      gld16(&Bs_l[d], Bl + boff[p] + k0);
    }
    __syncthreads();                 // drains vmcnt(0): staged tile visible

    s16x8 ah[4], al[4], bh[4], bl[4];
#pragma unroll
    for (int i = 0; i < 4; ++i) {
      int ao = (wr + (i << 4) + lm) * 32 + k8;
      ah[i] = *(const s16x8*)&As_h[ao];
      al[i] = *(const s16x8*)&As_l[ao];
      int bo = (wc + (i << 4) + lm) * 32 + k8;
      bh[i] = *(const s16x8*)&Bs_h[bo];
      bl[i] = *(const s16x8*)&Bs_l[bo];
    }
#pragma unroll
    for (int i = 0; i < 4; ++i)
#pragma unroll
      for (int j = 0; j < 4; ++j) {
        acc[i][j] = __builtin_amdgcn_mfma_f32_16x16x32_bf16(ah[i], bh[j], acc[i][j], 0, 0, 0);
        acc[i][j] = __builtin_amdgcn_mfma_f32_16x16x32_bf16(ah[i], bl[j], acc[i][j], 0, 0, 0);
        acc[i][j] = __builtin_amdgcn_mfma_f32_16x16x32_bf16(al[i], bh[j], acc[i][j], 0, 0, 0);
      }
    __syncthreads();                 // all reads done before next stage overwrites
  }

  // epilogue: C/D layout col = lane&15, row = (lane>>4)*4 + reg  [m89-verified]
  float bo4[4];
#pragma unroll
  for (int j = 0; j < 4; ++j) bo4[j] = b_out[n0 + wc + (j << 4) + lm];
  int rq = (l >> 4) << 2;
#pragma unroll
  for (int i = 0; i < 4; ++i)
#pragma unroll
    for (int q = 0; q < 4; ++q) {
      int m = m0 + wr + (i << 4) + rq + q;
      if (m >= M_) continue;
      float* orow = out + ((size_t)(m & 63) * TD + (m >> 6)) * V_ + n0 + wc + lm;
#pragma unroll
      for (int j = 0; j < 4; ++j)
        orow[j << 4] = acc[i][j][q] + bo4[j];
    }
}

// ---------------------------------------------------------------------------
// K6-fallback: fp32 tiled logits GEMM (used only if workspace too small).
// ---------------------------------------------------------------------------
__global__ __launch_bounds__(256) void k_logits(
    const float* __restrict__ Hall, const float* __restrict__ W_out,
    const float* __restrict__ b_out, float* __restrict__ out) {
  __shared__ float As[8][132];
  __shared__ float Bs[8][132];
  int m0 = blockIdx.x * 128;
  int n0 = blockIdx.y * 128;
  int t = threadIdx.x;
  int lr = t >> 1;              // 0..127
  int lk = (t & 1) * 4;         // 0 or 4
  int am = m0 + lr;
  if (am >= M_) am = M_ - 1;    // clamp loads; stores are guarded
  const float* arow = Hall + (size_t)am * 512;
  const float* brow = W_out + (size_t)(n0 + lr) * 512;
  int tx = t & 15, ty = t >> 4;
  float acc[8][8] = {};
  for (int k0 = 0; k0 < 512; k0 += 8) {
    float4 av = *(const float4*)(arow + k0 + lk);
    float4 bv = *(const float4*)(brow + k0 + lk);
    __syncthreads();
    As[lk + 0][lr] = av.x; As[lk + 1][lr] = av.y; As[lk + 2][lr] = av.z; As[lk + 3][lr] = av.w;
    Bs[lk + 0][lr] = bv.x; Bs[lk + 1][lr] = bv.y; Bs[lk + 2][lr] = bv.z; Bs[lk + 3][lr] = bv.w;
    __syncthreads();
    for (int kk = 0; kk < 8; ++kk) {
      float4 a0 = *(const float4*)&As[kk][ty * 4];
      float4 a1 = *(const float4*)&As[kk][64 + ty * 4];
      float4 b0 = *(const float4*)&Bs[kk][tx * 4];
      float4 b1 = *(const float4*)&Bs[kk][64 + tx * 4];
      float a[8] = {a0.x, a0.y, a0.z, a0.w, a1.x, a1.y, a1.z, a1.w};
      float bb[8] = {b0.x, b0.y, b0.z, b0.w, b1.x, b1.y, b1.z, b1.w};
      for (int i = 0; i < 8; ++i)
        for (int j = 0; j < 8; ++j) acc[i][j] += a[i] * bb[j];
    }
  }
  for (int i = 0; i < 8; ++i) {
    int mm = m0 + ((i < 4) ? (ty * 4 + i) : (64 + ty * 4 + i - 4));
    if (mm >= M_) continue;
    size_t base = ((size_t)(mm & 63) * TD + (mm >> 6)) * V_;   // out[b][t][v]
    for (int half = 0; half < 2; ++half) {
      int nn = n0 + half * 64 + tx * 4;
      int jb = half * 4;
      float4 v;
      v.x = acc[i][jb + 0] + b_out[nn + 0];
      v.y = acc[i][jb + 1] + b_out[nn + 1];
      v.z = acc[i][jb + 2] + b_out[nn + 2];
      v.w = acc[i][jb + 3] + b_out[nn + 3];
      *(float4*)(out + base + nn) = v;
    }
  }
}

// ---------------------------------------------------------------------------
// K7: argmax over V per (b,t); first-max tie rule (matches np/jnp.argmax).
// ---------------------------------------------------------------------------
__global__ __launch_bounds__(256) void k_argmax(
    const float* __restrict__ out, float* __restrict__ preds) {
  const float* row = out + ((size_t)blockIdx.x * TD + blockIdx.y) * V_;
  int t = threadIdx.x;
  float best = -INFINITY;
  int bidx = 0x7fffffff;
  for (int v = t; v < V_; v += 256) {
    float x = row[v];
    if (x > best) { best = x; bidx = v; }   // strict > keeps earliest within thread
  }
  __shared__ float s_v[256];
  __shared__ int s_i[256];
  s_v[t] = best; s_i[t] = bidx;
  __syncthreads();
  for (int off = 128; off; off >>= 1) {
    if (t < off) {
      float v2 = s_v[t + off]; int i2 = s_i[t + off];
      if (v2 > s_v[t] || (v2 == s_v[t] && i2 < s_i[t])) { s_v[t] = v2; s_i[t] = i2; }
    }
    __syncthreads();
  }
  if (t == 0) preds[(size_t)blockIdx.x * TD + blockIdx.y] = (float)s_i[0];
}

// ---------------------------------------------------------------------------
extern "C" void kernel_launch(void* const* d_in, const int* in_sizes, int n_in,
                              void* d_out, int out_size, void* d_ws, size_t ws_size,
                              hipStream_t stream) {
  const float* enc   = (const float*)d_in[0];
  const int*   tgt   = (const int*)d_in[1];
  const float* emb   = (const float*)d_in[2];
  const float* W1    = (const float*)d_in[3];
  const float* W2    = (const float*)d_in[5];
  const float* W3    = (const float*)d_in[7];
  const float* v_att = (const float*)d_in[9];
  const float* W_ih  = (const float*)d_in[10];
  const float* b_ih  = (const float*)d_in[11];
  const float* W_hh  = (const float*)d_in[12];
  const float* b_hh  = (const float*)d_in[13];
  const float* W_out = (const float*)d_in[14];
  const float* b_out = (const float*)d_in[15];
  float* out = (float*)d_out;

  float* ws      = (float*)d_ws;
  float* wenc    = ws;                                   // 512
  float* context = wenc + 512;                           // 64*512
  float* gctx    = context + 64 * 512;                   // 64*1536
  float* gic     = gctx + 64 * 1536;                     // 1856*1536
  float* h0      = gic + (size_t)M_ * 1536;              // 64*512
  float* Hall    = h0 + 64 * 512;                        // 29*64*512
  // split-bf16 arrays after Hall (shorts)
  unsigned short* W_hi = (unsigned short*)(Hall + (size_t)M_ * 512);
  unsigned short* W_lo = W_hi + (size_t)V_ * 512;
  unsigned short* H_hi = W_lo + (size_t)V_ * 512;
  unsigned short* H_lo = H_hi + (size_t)M_ * 512;
  size_t need = (size_t)((char*)(H_lo + (size_t)M_ * 512) - (char*)d_ws);
  bool use_mfma = (ws_size >= need);

  if (use_mfma) {
    // independent of everything else; do it first
    k_split<<<1024, 256, 0, stream>>>(W_out, W_hi, W_lo, V_ * 512 / 4);
  }

  hipMemsetAsync(h0, 0, 64 * 512 * sizeof(float), stream);
  k_attn_vec<<<1, 512, 0, stream>>>(W1, W2, W3, v_att, wenc);
  k_score_ctx<<<64, 512, 0, stream>>>(enc, wenc, context);
  k_gctx<<<dim3(64, 24), 256, 0, stream>>>(context, W_ih, b_ih, gctx);
  k_giemb<<<dim3(29, 24), 256, 0, stream>>>(emb, tgt, W_ih, gctx, gic);
  for (int t = 0; t < TD; ++t) {
    const float* hp = (t == 0) ? h0 : (Hall + (size_t)(t - 1) * 64 * 512);
    k_step<<<dim3(64, 8), 256, 0, stream>>>(hp, W_hh, b_hh,
                                            gic + (size_t)t * 64 * 1536,
                                            Hall + (size_t)t * 64 * 512);
  }
  if (use_mfma) {
    k_split<<<512, 256, 0, stream>>>(Hall, H_hi, H_lo, M_ * 512 / 4);
    k_logits_mfma<<<dim3(15, 250), 256, 0, stream>>>(H_hi, H_lo, W_hi, W_lo, b_out, out);
  } else {
    k_logits<<<dim3(15, 250), 256, 0, stream>>>(Hall, W_out, b_out, out);
  }
  k_argmax<<<dim3(64, TD), 256, 0, stream>>>(out, out + (size_t)M_ * V_);
}